// Round 5
// baseline (411.534 us; speedup 1.0000x reference)
//
#include <hip/hip_runtime.h>
#include <hip/hip_bf16.h>
#include <cmath>

#define BETA 0.3f
#define LAMBDA_PHY 0.15f

#define BM 256
#define BN 256
#define BK 64
#define NT 256

typedef __bf16 bf16x8 __attribute__((ext_vector_type(8)));
typedef float f32x4 __attribute__((ext_vector_type(4)));

#define AS1 __attribute__((address_space(1)))
#define AS3 __attribute__((address_space(3)))

#define FENCE() asm volatile("" ::: "memory")
#define BARRIER() do { FENCE(); __builtin_amdgcn_s_barrier(); FENCE(); } while (0)
#define WAITV0() asm volatile("s_waitcnt vmcnt(0)" ::: "memory")

__device__ __forceinline__ unsigned short f2bf_rn(float f) {
    unsigned int u = __builtin_bit_cast(unsigned int, f);
    return (unsigned short)((u + 0x7FFFu + ((u >> 16) & 1u)) >> 16);
}

__device__ __forceinline__ float bf2f(unsigned short u) {
    return __builtin_bit_cast(float, (unsigned int)u << 16);
}

__device__ __forceinline__ float softplus_f(float x) {
    return fmaxf(x, 0.0f) + __logf(1.0f + __expf(-fabsf(x)));
}

__device__ __forceinline__ float smooth_l1_f(float d) {
    float ad = fabsf(d);
    return (ad < BETA) ? (0.5f / BETA) * d * d : (ad - 0.5f * BETA);
}

// ---------------------------------------------------------------------------
// Kernel 1: adjacency (int32 ZxZ) -> bf16 mask (ZxZ, K-contig) + invdeg + hasnb
__global__ void k_prep(const int* __restrict__ adj, unsigned short* __restrict__ maskbf,
                       float* __restrict__ invdeg, float* __restrict__ hasnb, int Z) {
    int z = blockIdx.x;
    int t = threadIdx.x;
    const int* row = adj + (size_t)z * Z;
    unsigned short* mrow = maskbf + (size_t)z * Z;
    int cnt = 0;
    for (int n = t; n < Z; n += blockDim.x) {
        int a = (row[n] > 0);
        mrow[n] = a ? (unsigned short)0x3F80 : (unsigned short)0;  // bf16 1.0 / 0.0
        cnt += a;
    }
    for (int o = 32; o; o >>= 1) cnt += __shfl_down(cnt, o);
    __shared__ int rs[4];
    int lane = t & 63, wave = t >> 6;
    if (lane == 0) rs[wave] = cnt;
    __syncthreads();
    if (t == 0) {
        int deg = rs[0] + rs[1] + rs[2] + rs[3];
        invdeg[z] = (deg > 0) ? 1.0f / (float)deg : 1.0f;
        hasnb[z]  = (deg > 0) ? 1.0f : 0.0f;
    }
}

// ---------------------------------------------------------------------------
// Kernel 2: fp32 -> bf16 (RN), 8 elems/thread, vectorized
__global__ void k_conv(const float* __restrict__ src, uint4* __restrict__ dst, long n8) {
    long i = (long)blockIdx.x * blockDim.x + threadIdx.x;
    long stride = (long)gridDim.x * blockDim.x;
    for (; i < n8; i += stride) {
        const float4* s = (const float4*)(src + i * 8);
        float4 a = s[0], b = s[1];
        uint4 o;
        o.x = (unsigned)f2bf_rn(a.x) | ((unsigned)f2bf_rn(a.y) << 16);
        o.y = (unsigned)f2bf_rn(a.z) | ((unsigned)f2bf_rn(a.w) << 16);
        o.z = (unsigned)f2bf_rn(b.x) | ((unsigned)f2bf_rn(b.y) << 16);
        o.w = (unsigned)f2bf_rn(b.z) | ((unsigned)f2bf_rn(b.w) << 16);
        dst[i] = o;
    }
}

// ---------------------------------------------------------------------------
// Kernel 3: 256x256 bf16 GEMM, 4 waves (2x2), per-wave 128x128 output.
// __launch_bounds__(256,1): 1 wave/SIMD -> 512 unified regs/wave, no spill
// (NT=512 structurally caps at 256 regs -> 52 MB spill, rounds 2-4).
// One barrier per K-tile: stage-next issued at tile start, own vmcnt(0)
// after ~620 cyc of MFMA, s_barrier. Phases are barrier-free dataflow.
// T2 XOR swizzle (src-side pre-swizzle + same XOR on ds_read), T1 XCD swizzle.
__global__ __launch_bounds__(NT, 1) void k_gemm(
    const unsigned short* __restrict__ Abf,   // [M][K] bf16 ctemps
    const unsigned short* __restrict__ Bbf,   // [N][K] bf16 mask
    const float* __restrict__ preds,
    const float* __restrict__ targets,
    const float* __restrict__ invdeg,
    const float* __restrict__ hasnb,
    float* __restrict__ partials,
    int M, int N, int K)
{
    __shared__ unsigned short As[2][256 * 64];   // [buf][row*64 + col]
    __shared__ unsigned short Bs[2][256 * 64];

    const int nwg = gridDim.x;
    const int ob = blockIdx.x;
    const int bid = (nwg % 8 == 0) ? ((ob % 8) * (nwg / 8) + ob / 8) : ob;  // T1
    const int ntiles = N / BN;
    const int mt = bid / ntiles;
    const int nt = bid % ntiles;
    const int row0 = mt * BM;
    const int col0 = nt * BN;
    const int t = threadIdx.x;
    const int lane = t & 63;
    const int wave = t >> 6;
    const int wm = wave >> 1;             // 2x2 wave grid; each wave 128x128 out
    const int wn = wave & 1;
    const int fr = lane & 15;
    const int fq = lane >> 4;
    const int fr7 = fr & 7;

    // staging: thread t -> row tr (+32 per round), 16B slot tc; src col-slot
    // pre-swizzled. (32 % 8 == 0 so row&7 == tr&7 for all rounds -> cs const.)
    const int tr = t >> 3;                // 0..31
    const int tc = t & 7;                 // 16B slot 0..7
    const int cs = tc ^ (tr & 7);         // swizzled global col-slot

    f32x4 acc[8][8];
#pragma unroll
    for (int m = 0; m < 8; ++m)
#pragma unroll
        for (int n = 0; n < 8; ++n)
            acc[m][n] = (f32x4){0.f, 0.f, 0.f, 0.f};

    const unsigned short* Ab = Abf + (size_t)row0 * K;
    const unsigned short* Bb = Bbf + (size_t)col0 * K;

#define STAGE(dstLds, srcG, kt) do {                                                         \
    _Pragma("unroll")                                                                        \
    for (int r_ = 0; r_ < 8; ++r_)                                                           \
        __builtin_amdgcn_global_load_lds(                                                    \
            (const AS1 void*)((srcG) + (size_t)(r_ * 32 + tr) * K + (kt) * BK + cs * 8),     \
            (AS3 void*)(&(dstLds)[(r_ * 32 + tr) * 64 + tc * 8]), 16, 0, 0);                 \
} while (0)

    bf16x8 af[8][2];   // full A column of this wave's 128 rows: [mi][kk]
    bf16x8 bv[2][2];   // current B n-pair: [ni][kk]

#define LOAD_AF(buf) do {                                                                    \
    _Pragma("unroll")                                                                        \
    for (int mi_ = 0; mi_ < 8; ++mi_)                                                        \
    _Pragma("unroll")                                                                        \
    for (int kk_ = 0; kk_ < 2; ++kk_)                                                        \
        af[mi_][kk_] = *(const bf16x8*)&As[buf][(wm * 128 + mi_ * 16 + fr) * 64 +            \
                                               (((kk_ * 4 + fq) ^ fr7) * 8)];                \
} while (0)

#define LOAD_BV(buf, q) do {                                                                 \
    _Pragma("unroll")                                                                        \
    for (int ni_ = 0; ni_ < 2; ++ni_)                                                        \
    _Pragma("unroll")                                                                        \
    for (int kk_ = 0; kk_ < 2; ++kk_)                                                        \
        bv[ni_][kk_] = *(const bf16x8*)&Bs[buf][(wn * 128 + (q) * 32 + ni_ * 16 + fr) * 64 + \
                                               (((kk_ * 4 + fq) ^ fr7) * 8)];                \
} while (0)

#define MFMA_P(q) do {                                                                       \
    _Pragma("unroll")                                                                        \
    for (int kk_ = 0; kk_ < 2; ++kk_)                                                        \
    _Pragma("unroll")                                                                        \
    for (int mi_ = 0; mi_ < 8; ++mi_)                                                        \
    _Pragma("unroll")                                                                        \
    for (int ni_ = 0; ni_ < 2; ++ni_)                                                        \
        acc[mi_][(q) * 2 + ni_] = __builtin_amdgcn_mfma_f32_16x16x32_bf16(                   \
            af[mi_][kk_], bv[ni_][kk_], acc[mi_][(q) * 2 + ni_], 0, 0, 0);                   \
} while (0)

    const int nk = K / BK;
    STAGE(As[0], Ab, 0); STAGE(Bs[0], Bb, 0);
    WAITV0();
    BARRIER();

    int cur = 0;
    for (int ti = 0; ti < nk; ++ti) {
        const int nb = cur ^ 1;
        if (ti + 1 < nk) { STAGE(As[nb], Ab, ti + 1); STAGE(Bs[nb], Bb, ti + 1); }
        LOAD_AF(cur);
#pragma unroll
        for (int q = 0; q < 4; ++q) {
            LOAD_BV(cur, q);
            MFMA_P(q);
        }
        WAITV0();                 // own 16 stage loads; issued ~620 MFMA-cycles ago
        BARRIER();
        cur = nb;
    }

#undef STAGE
#undef LOAD_AF
#undef LOAD_BV
#undef MFMA_P

    // Fused epilogue. C/D frag layout: col=lane&15, row=(lane>>4)*4+reg.
    // block row = wm*128 + m*16 + fq*4 + j ; block col = wn*128 + n*16 + fr
    float vsum = 0.f, ssum = 0.f;
#pragma unroll
    for (int n = 0; n < 8; ++n) {
        const int z = col0 + wn * 128 + n * 16 + fr;
        const float idg = invdeg[z];
        const float hnb = hasnb[z];
#pragma unroll
        for (int m = 0; m < 8; ++m) {
            const int rb = row0 + wm * 128 + m * 16 + fq * 4;
#pragma unroll
            for (int j = 0; j < 4; ++j) {
                const size_t idx = (size_t)(rb + j) * N + z;
                float avg = acc[m][n][j] * idg;
                float c = bf2f(Abf[idx]);          // bf16 ctemps (saves 1/3 fetch)
                float p = preds[idx];
                float tg = targets[idx];
                float x = (c - avg) * (p - c);
                vsum += softplus_f(x) * hnb;
                ssum += smooth_l1_f(p - tg);
            }
        }
    }
    for (int o = 32; o; o >>= 1) { vsum += __shfl_down(vsum, o); ssum += __shfl_down(ssum, o); }
    __shared__ float rv[4], rsm[4];
    if (lane == 0) { rv[wave] = vsum; rsm[wave] = ssum; }
    __syncthreads();
    if (t == 0) {
        partials[2 * (size_t)ob]     = rv[0] + rv[1] + rv[2] + rv[3];
        partials[2 * (size_t)ob + 1] = rsm[0] + rsm[1] + rsm[2] + rsm[3];
    }
}

// ---------------------------------------------------------------------------
// Kernel 4: deterministic fixed-order final reduction
__global__ void k_finalize(const float* __restrict__ partials, int nblk,
                           float* __restrict__ out, float invBZ) {
    __shared__ float sv[256], ss[256];
    int t = threadIdx.x;
    float v = 0.f, s = 0.f;
    for (int i = t; i < nblk; i += 256) { v += partials[2 * (size_t)i]; s += partials[2 * (size_t)i + 1]; }
    sv[t] = v; ss[t] = s;
    __syncthreads();
    for (int o = 128; o; o >>= 1) {
        if (t < o) { sv[t] += sv[t + o]; ss[t] += ss[t + o]; }
        __syncthreads();
    }
    if (t == 0) {
        float phys = sv[0] * invBZ;
        float pred = ss[0] * invBZ;
        out[0] = pred + LAMBDA_PHY * phys;
        out[1] = phys;
    }
}

// ---------------------------------------------------------------------------
// Fallback path (only if ws too small / odd shapes): fp32, atomics into ws[0..1]
__global__ void k_zero2(float* p) { if (threadIdx.x < 2) p[threadIdx.x] = 0.f; }

__global__ void k_fallback(const float* __restrict__ preds, const float* __restrict__ targets,
                           const float* __restrict__ ctemps, const int* __restrict__ adj,
                           float* __restrict__ acc2, int B, int Z) {
    extern __shared__ float crow[];
    int nzb = (Z + 255) / 256;
    int b = blockIdx.x / nzb;
    int zb = blockIdx.x % nzb;
    int t = threadIdx.x;
    const float* cr = ctemps + (size_t)b * Z;
    for (int n = t; n < Z; n += 256) crow[n] = cr[n];
    __syncthreads();
    int z = zb * 256 + t;
    float vsum = 0.f, ssum = 0.f;
    if (z < Z) {
        const int* arow = adj + (size_t)z * Z;
        float sum = 0.f; int deg = 0;
        for (int n = 0; n < Z; ++n) {
            if (arow[n] > 0) { sum += crow[n]; ++deg; }
        }
        float avg = (deg > 0) ? sum / (float)deg : 0.f;
        float c = crow[z];
        size_t idx = (size_t)b * Z + z;
        float p = preds[idx];
        float x = (c - avg) * (p - c);
        vsum = (deg > 0) ? softplus_f(x) : 0.f;
        ssum = smooth_l1_f(p - targets[idx]);
    }
    for (int o = 32; o; o >>= 1) { vsum += __shfl_down(vsum, o); ssum += __shfl_down(ssum, o); }
    __shared__ float rv[4], rs2[4];
    int lane = t & 63, wave = t >> 6;
    if (lane == 0) { rv[wave] = vsum; rs2[wave] = ssum; }
    __syncthreads();
    if (t == 0) {
        atomicAdd(&acc2[0], rv[0] + rv[1] + rv[2] + rv[3]);
        atomicAdd(&acc2[1], rs2[0] + rs2[1] + rs2[2] + rs2[3]);
    }
}

// ---------------------------------------------------------------------------
extern "C" void kernel_launch(void* const* d_in, const int* in_sizes, int n_in,
                              void* d_out, int out_size, void* d_ws, size_t ws_size,
                              hipStream_t stream) {
    const float* preds   = (const float*)d_in[0];
    const float* targets = (const float*)d_in[1];
    const float* ctemps  = (const float*)d_in[2];
    const int*   adj     = (const int*)d_in[3];
    float* out = (float*)d_out;

    long zz = in_sizes[3];
    int Z = (int)llround(sqrt((double)zz));
    int B = in_sizes[1] / Z;

    size_t off = 0;
    size_t maskOff = off; off += (size_t)Z * Z * 2;
    size_t cbfOff  = off; off += (size_t)B * Z * 2;
    size_t idgOff  = off; off += (size_t)Z * 4;
    size_t hnbOff  = off; off += (size_t)Z * 4;
    int nblk = (Z > 0 && B > 0 && (B % BM) == 0 && (Z % BN) == 0) ? (B / BM) * (Z / BN) : 0;
    size_t partOff = off; off += (size_t)(nblk > 0 ? nblk : 1) * 2 * 4;

    bool main_ok = (B % BM == 0) && (Z % BN == 0) && (Z % BK == 0) && (ws_size >= off);

    float invBZ = (float)(1.0 / ((double)B * (double)Z));

    if (main_ok) {
        char* ws = (char*)d_ws;
        unsigned short* maskbf = (unsigned short*)(ws + maskOff);
        unsigned short* cbf    = (unsigned short*)(ws + cbfOff);
        float* idg      = (float*)(ws + idgOff);
        float* hnb      = (float*)(ws + hnbOff);
        float* partials = (float*)(ws + partOff);

        k_prep<<<Z, 256, 0, stream>>>(adj, maskbf, idg, hnb, Z);
        long n8 = (long)B * Z / 8;
        k_conv<<<2048, 256, 0, stream>>>(ctemps, (uint4*)cbf, n8);
        k_gemm<<<nblk, NT, 0, stream>>>(cbf, maskbf, preds, targets, idg, hnb, partials, B, Z, Z);
        k_finalize<<<1, 256, 0, stream>>>(partials, nblk, out, invBZ);
    } else {
        float* acc2 = (float*)d_ws;
        k_zero2<<<1, 64, 0, stream>>>(acc2);
        int nzb = (Z + 255) / 256;
        k_fallback<<<B * nzb, 256, (size_t)Z * 4, stream>>>(preds, targets, ctemps, adj, acc2, B, Z);
        k_finalize<<<1, 256, 0, stream>>>(acc2, 1, out, invBZ);
    }
}

// Round 6
// 330.851 us; speedup vs baseline: 1.2439x; 1.2439x over previous
//
#include <hip/hip_runtime.h>
#include <hip/hip_bf16.h>
#include <cmath>

#define BETA 0.3f
#define LAMBDA_PHY 0.15f

#define BM 256
#define BN 256
#define BK 64
#define NT 512

typedef __bf16 bf16x8 __attribute__((ext_vector_type(8)));
typedef float f32x4 __attribute__((ext_vector_type(4)));

#define AS1 __attribute__((address_space(1)))
#define AS3 __attribute__((address_space(3)))

#define FENCE() asm volatile("" ::: "memory")
#define BARRIER() do { FENCE(); __builtin_amdgcn_s_barrier(); FENCE(); } while (0)
#define WAITV4() asm volatile("s_waitcnt vmcnt(4)" ::: "memory")
#define WAITV0() asm volatile("s_waitcnt vmcnt(0)" ::: "memory")

__device__ __forceinline__ unsigned short f2bf_rn(float f) {
    unsigned int u = __builtin_bit_cast(unsigned int, f);
    return (unsigned short)((u + 0x7FFFu + ((u >> 16) & 1u)) >> 16);
}

__device__ __forceinline__ float bf2f(unsigned short u) {
    return __builtin_bit_cast(float, (unsigned int)u << 16);
}

__device__ __forceinline__ float softplus_f(float x) {
    return fmaxf(x, 0.0f) + __logf(1.0f + __expf(-fabsf(x)));
}

__device__ __forceinline__ float smooth_l1_f(float d) {
    float ad = fabsf(d);
    return (ad < BETA) ? (0.5f / BETA) * d * d : (ad - 0.5f * BETA);
}

// ---------------------------------------------------------------------------
// Kernel 1: adjacency (int32 ZxZ) -> bf16 mask (ZxZ, K-contig) + invdeg + hasnb
__global__ void k_prep(const int* __restrict__ adj, unsigned short* __restrict__ maskbf,
                       float* __restrict__ invdeg, float* __restrict__ hasnb, int Z) {
    int z = blockIdx.x;
    int t = threadIdx.x;
    const int* row = adj + (size_t)z * Z;
    unsigned short* mrow = maskbf + (size_t)z * Z;
    int cnt = 0;
    for (int n = t; n < Z; n += blockDim.x) {
        int a = (row[n] > 0);
        mrow[n] = a ? (unsigned short)0x3F80 : (unsigned short)0;  // bf16 1.0 / 0.0
        cnt += a;
    }
    for (int o = 32; o; o >>= 1) cnt += __shfl_down(cnt, o);
    __shared__ int rs[4];
    int lane = t & 63, wave = t >> 6;
    if (lane == 0) rs[wave] = cnt;
    __syncthreads();
    if (t == 0) {
        int deg = rs[0] + rs[1] + rs[2] + rs[3];
        invdeg[z] = (deg > 0) ? 1.0f / (float)deg : 1.0f;
        hasnb[z]  = (deg > 0) ? 1.0f : 0.0f;
    }
}

// ---------------------------------------------------------------------------
// Kernel 2: fp32 -> bf16 (RN), 8 elems/thread, vectorized
__global__ void k_conv(const float* __restrict__ src, uint4* __restrict__ dst, long n8) {
    long i = (long)blockIdx.x * blockDim.x + threadIdx.x;
    long stride = (long)gridDim.x * blockDim.x;
    for (; i < n8; i += stride) {
        const float4* s = (const float4*)(src + i * 8);
        float4 a = s[0], b = s[1];
        uint4 o;
        o.x = (unsigned)f2bf_rn(a.x) | ((unsigned)f2bf_rn(a.y) << 16);
        o.y = (unsigned)f2bf_rn(a.z) | ((unsigned)f2bf_rn(a.w) << 16);
        o.z = (unsigned)f2bf_rn(b.x) | ((unsigned)f2bf_rn(b.y) << 16);
        o.w = (unsigned)f2bf_rn(b.z) | ((unsigned)f2bf_rn(b.w) << 16);
        dst[i] = o;
    }
}

// ---------------------------------------------------------------------------
// Kernel 3: 256x256 bf16 GEMM, 8 waves (2x4, 128x64 out each), 8-phase
// counted-vmcnt schedule. Register budget at 2 waves/SIMD = 256/wave:
// acc[8][4]=128 (AGPR) + arch 128. In-loop arch live-set kept <=128 by
// holding only bv[2] (one K-half, 16 VGPR) instead of bv[2][2] — second
// K-half load overlaps the first 8-MFMA cluster. (Round-4's bv[2][2]
// pushed arch past 128 -> 52 MB loop spill.)
__global__ __launch_bounds__(NT) void k_gemm(
    const unsigned short* __restrict__ Abf,   // [M][K] bf16 ctemps
    const unsigned short* __restrict__ Bbf,   // [N][K] bf16 mask
    const float* __restrict__ preds,
    const float* __restrict__ targets,
    const float* __restrict__ invdeg,
    const float* __restrict__ hasnb,
    float* __restrict__ partials,
    int M, int N, int K)
{
    __shared__ unsigned short As[2][2][128 * 64];   // [buf][half][hr*64 + col]
    __shared__ unsigned short Bs[2][2][128 * 64];

    const int nwg = gridDim.x;
    const int ob = blockIdx.x;
    const int bid = (nwg % 8 == 0) ? ((ob % 8) * (nwg / 8) + ob / 8) : ob;  // T1
    const int ntiles = N / BN;
    const int mt = bid / ntiles;
    const int nt = bid % ntiles;
    const int row0 = mt * BM;
    const int col0 = nt * BN;
    const int t = threadIdx.x;
    const int lane = t & 63;
    const int wave = t >> 6;
    const int wm = wave >> 2;             // 2x4 wave grid
    const int wn = wave & 3;
    const int fr = lane & 15;
    const int fq = lane >> 4;
    const int fr7 = fr & 7;

    // staging: thread t -> (tr, tc); source col-slot pre-swizzled (T2)
    const int tr = t >> 3;                // 0..63
    const int tc = t & 7;                 // 16B slot 0..7
    const int cs = tc ^ (tr & 7);         // swizzled global col-slot

    f32x4 acc[8][4];
#pragma unroll
    for (int m = 0; m < 8; ++m)
#pragma unroll
        for (int n = 0; n < 4; ++n)
            acc[m][n] = (f32x4){0.f, 0.f, 0.f, 0.f};

    const unsigned short* Ab = Abf + (size_t)row0 * K;
    const unsigned short* Bb = Bbf + (size_t)col0 * K;

#define STAGE_A(buf, h, kt) do {                                                             \
    _Pragma("unroll")                                                                        \
    for (int r_ = 0; r_ < 2; ++r_)                                                           \
        __builtin_amdgcn_global_load_lds(                                                    \
            (const AS1 void*)(Ab + (size_t)(r_ * 128 + (h) * 64 + tr) * K + (kt) * BK + cs * 8), \
            (AS3 void*)(&As[buf][h][(r_ * 64 + tr) * 64 + tc * 8]), 16, 0, 0);               \
} while (0)

#define STAGE_B(buf, h, kt) do {                                                             \
    _Pragma("unroll")                                                                        \
    for (int r_ = 0; r_ < 2; ++r_)                                                           \
        __builtin_amdgcn_global_load_lds(                                                    \
            (const AS1 void*)(Bb + (size_t)((r_ * 2 + (tr >> 5)) * 64 + (h) * 32 + (tr & 31)) * K + (kt) * BK + cs * 8), \
            (AS3 void*)(&Bs[buf][h][(r_ * 64 + tr) * 64 + tc * 8]), 16, 0, 0);               \
} while (0)

    bf16x8 af[4][2];   // A frags of current A-half: [mi][kk]  (64 VGPR)
    bf16x8 bv[2];      // B frags of current B-half, ONE kk    (16 VGPR)

#define LOAD_AF(buf, mq) do {                                                                \
    _Pragma("unroll")                                                                        \
    for (int mi_ = 0; mi_ < 4; ++mi_)                                                        \
    _Pragma("unroll")                                                                        \
    for (int kk_ = 0; kk_ < 2; ++kk_)                                                        \
        af[mi_][kk_] = *(const bf16x8*)&As[buf][mq][(wm * 64 + mi_ * 16 + fr) * 64 +         \
                                                    (((kk_ * 4 + fq) ^ fr7) * 8)];           \
} while (0)

#define LOAD_BV(buf, nq, kk) do {                                                            \
    _Pragma("unroll")                                                                        \
    for (int ni_ = 0; ni_ < 2; ++ni_)                                                        \
        bv[ni_] = *(const bf16x8*)&Bs[buf][nq][(wn * 32 + ni_ * 16 + fr) * 64 +              \
                                               ((((kk) * 4 + fq) ^ fr7) * 8)];               \
} while (0)

#define MFMA_H(mq, nq, kk) do {                                                              \
    __builtin_amdgcn_s_setprio(1);                                                           \
    _Pragma("unroll")                                                                        \
    for (int mi_ = 0; mi_ < 4; ++mi_)                                                        \
    _Pragma("unroll")                                                                        \
    for (int ni_ = 0; ni_ < 2; ++ni_)                                                        \
        acc[(mq) * 4 + mi_][(nq) * 2 + ni_] = __builtin_amdgcn_mfma_f32_16x16x32_bf16(       \
            af[mi_][kk], bv[ni_], acc[(mq) * 4 + mi_][(nq) * 2 + ni_], 0, 0, 0);             \
    __builtin_amdgcn_s_setprio(0);                                                           \
} while (0)

    const int nk = K / BK;
    // Prologue: stage tile 0 in order A0,B0,B1,A1; retire A0,B0 before loop.
    STAGE_A(0, 0, 0); STAGE_B(0, 0, 0); STAGE_B(0, 1, 0); STAGE_A(0, 1, 0);
    WAITV4();
    BARRIER();

    int cur = 0;
    for (int ti = 0; ti < nk - 1; ++ti) {
        const int nb = cur ^ 1;
        // R0: quadrant (A0,B0). Reads pre-barrier; stage (ti+1,A0).
        LOAD_AF(cur, 0);
        LOAD_BV(cur, 0, 0);
        STAGE_A(nb, 0, ti + 1);
        WAITV4();                 // retires (ti,B1) — read at R1
        BARRIER();
        MFMA_H(0, 0, 0);
        LOAD_BV(cur, 0, 1);
        MFMA_H(0, 0, 1);
        BARRIER();
        // R1: quadrant (A0,B1) — af reused; stage (ti+1,B0).
        LOAD_BV(cur, 1, 0);
        STAGE_B(nb, 0, ti + 1);
        WAITV4();                 // retires (ti,A1) — read at R2
        BARRIER();
        MFMA_H(0, 1, 0);
        LOAD_BV(cur, 1, 1);
        MFMA_H(0, 1, 1);
        BARRIER();
        // R2: quadrant (A1,B1); stage (ti+1,B1).
        LOAD_AF(cur, 1);
        LOAD_BV(cur, 1, 0);
        STAGE_B(nb, 1, ti + 1);
        BARRIER();
        MFMA_H(1, 1, 0);
        LOAD_BV(cur, 1, 1);
        MFMA_H(1, 1, 1);
        BARRIER();
        // R3: quadrant (A1,B0); stage (ti+1,A1).
        LOAD_BV(cur, 0, 0);
        STAGE_A(nb, 1, ti + 1);
        WAITV4();                 // retires (ti+1,A0),(ti+1,B0) — read next R0
        BARRIER();
        MFMA_H(1, 0, 0);
        LOAD_BV(cur, 0, 1);
        MFMA_H(1, 0, 1);
        BARRIER();
        cur = nb;
    }
    // Tail tile: drain everything once, then compute all 4 quadrants.
    WAITV0();
    BARRIER();
    LOAD_AF(cur, 0);
    LOAD_BV(cur, 0, 0);  MFMA_H(0, 0, 0);
    LOAD_BV(cur, 0, 1);  MFMA_H(0, 0, 1);
    LOAD_BV(cur, 1, 0);  MFMA_H(0, 1, 0);
    LOAD_BV(cur, 1, 1);  MFMA_H(0, 1, 1);
    LOAD_AF(cur, 1);
    LOAD_BV(cur, 1, 0);  MFMA_H(1, 1, 0);
    LOAD_BV(cur, 1, 1);  MFMA_H(1, 1, 1);
    LOAD_BV(cur, 0, 0);  MFMA_H(1, 0, 0);
    LOAD_BV(cur, 0, 1);  MFMA_H(1, 0, 1);

#undef STAGE_A
#undef STAGE_B
#undef LOAD_AF
#undef LOAD_BV
#undef MFMA_H

    // Fused epilogue. C/D frag layout: col=lane&15, row=(lane>>4)*4+reg.
    // block row = wm*128 + (m>>2)*64 + (m&3)*16 + fq*4 + j
    // block col = wn*64  + (n>>1)*32 + (n&1)*16 + fr
    float vsum = 0.f, ssum = 0.f;
#pragma unroll
    for (int n = 0; n < 4; ++n) {
        const int z = col0 + wn * 64 + (n >> 1) * 32 + (n & 1) * 16 + fr;
        const float idg = invdeg[z];
        const float hnb = hasnb[z];
#pragma unroll
        for (int m = 0; m < 8; ++m) {
            const int rb = row0 + wm * 128 + (m >> 2) * 64 + (m & 3) * 16 + fq * 4;
#pragma unroll
            for (int j = 0; j < 4; ++j) {
                const size_t idx = (size_t)(rb + j) * N + z;
                float avg = acc[m][n][j] * idg;
                float c = bf2f(Abf[idx]);          // bf16 ctemps (saves 1/3 fetch)
                float p = preds[idx];
                float tg = targets[idx];
                float x = (c - avg) * (p - c);
                vsum += softplus_f(x) * hnb;
                ssum += smooth_l1_f(p - tg);
            }
        }
    }
    for (int o = 32; o; o >>= 1) { vsum += __shfl_down(vsum, o); ssum += __shfl_down(ssum, o); }
    __shared__ float rv[8], rsm[8];
    if (lane == 0) { rv[wave] = vsum; rsm[wave] = ssum; }
    __syncthreads();
    if (t == 0) {
        float v = 0.f, s = 0.f;
#pragma unroll
        for (int w = 0; w < 8; ++w) { v += rv[w]; s += rsm[w]; }
        partials[2 * (size_t)ob]     = v;
        partials[2 * (size_t)ob + 1] = s;
    }
}

// ---------------------------------------------------------------------------
// Kernel 4: deterministic fixed-order final reduction
__global__ void k_finalize(const float* __restrict__ partials, int nblk,
                           float* __restrict__ out, float invBZ) {
    __shared__ float sv[256], ss[256];
    int t = threadIdx.x;
    float v = 0.f, s = 0.f;
    for (int i = t; i < nblk; i += 256) { v += partials[2 * (size_t)i]; s += partials[2 * (size_t)i + 1]; }
    sv[t] = v; ss[t] = s;
    __syncthreads();
    for (int o = 128; o; o >>= 1) {
        if (t < o) { sv[t] += sv[t + o]; ss[t] += ss[t + o]; }
        __syncthreads();
    }
    if (t == 0) {
        float phys = sv[0] * invBZ;
        float pred = ss[0] * invBZ;
        out[0] = pred + LAMBDA_PHY * phys;
        out[1] = phys;
    }
}

// ---------------------------------------------------------------------------
// Fallback path (only if ws too small / odd shapes): fp32, atomics into ws[0..1]
__global__ void k_zero2(float* p) { if (threadIdx.x < 2) p[threadIdx.x] = 0.f; }

__global__ void k_fallback(const float* __restrict__ preds, const float* __restrict__ targets,
                           const float* __restrict__ ctemps, const int* __restrict__ adj,
                           float* __restrict__ acc2, int B, int Z) {
    extern __shared__ float crow[];
    int nzb = (Z + 255) / 256;
    int b = blockIdx.x / nzb;
    int zb = blockIdx.x % nzb;
    int t = threadIdx.x;
    const float* cr = ctemps + (size_t)b * Z;
    for (int n = t; n < Z; n += 256) crow[n] = cr[n];
    __syncthreads();
    int z = zb * 256 + t;
    float vsum = 0.f, ssum = 0.f;
    if (z < Z) {
        const int* arow = adj + (size_t)z * Z;
        float sum = 0.f; int deg = 0;
        for (int n = 0; n < Z; ++n) {
            if (arow[n] > 0) { sum += crow[n]; ++deg; }
        }
        float avg = (deg > 0) ? sum / (float)deg : 0.f;
        float c = crow[z];
        size_t idx = (size_t)b * Z + z;
        float p = preds[idx];
        float x = (c - avg) * (p - c);
        vsum = (deg > 0) ? softplus_f(x) : 0.f;
        ssum = smooth_l1_f(p - targets[idx]);
    }
    for (int o = 32; o; o >>= 1) { vsum += __shfl_down(vsum, o); ssum += __shfl_down(ssum, o); }
    __shared__ float rv[4], rs2[4];
    int lane = t & 63, wave = t >> 6;
    if (lane == 0) { rv[wave] = vsum; rs2[wave] = ssum; }
    __syncthreads();
    if (t == 0) {
        atomicAdd(&acc2[0], rv[0] + rv[1] + rv[2] + rv[3]);
        atomicAdd(&acc2[1], rs2[0] + rs2[1] + rs2[2] + rs2[3]);
    }
}

// ---------------------------------------------------------------------------
extern "C" void kernel_launch(void* const* d_in, const int* in_sizes, int n_in,
                              void* d_out, int out_size, void* d_ws, size_t ws_size,
                              hipStream_t stream) {
    const float* preds   = (const float*)d_in[0];
    const float* targets = (const float*)d_in[1];
    const float* ctemps  = (const float*)d_in[2];
    const int*   adj     = (const int*)d_in[3];
    float* out = (float*)d_out;

    long zz = in_sizes[3];
    int Z = (int)llround(sqrt((double)zz));
    int B = in_sizes[1] / Z;

    size_t off = 0;
    size_t maskOff = off; off += (size_t)Z * Z * 2;
    size_t cbfOff  = off; off += (size_t)B * Z * 2;
    size_t idgOff  = off; off += (size_t)Z * 4;
    size_t hnbOff  = off; off += (size_t)Z * 4;
    int nblk = (Z > 0 && B > 0 && (B % BM) == 0 && (Z % BN) == 0) ? (B / BM) * (Z / BN) : 0;
    size_t partOff = off; off += (size_t)(nblk > 0 ? nblk : 1) * 2 * 4;

    bool main_ok = (B % BM == 0) && (Z % BN == 0) && (Z % BK == 0) && (ws_size >= off);

    float invBZ = (float)(1.0 / ((double)B * (double)Z));

    if (main_ok) {
        char* ws = (char*)d_ws;
        unsigned short* maskbf = (unsigned short*)(ws + maskOff);
        unsigned short* cbf    = (unsigned short*)(ws + cbfOff);
        float* idg      = (float*)(ws + idgOff);
        float* hnb      = (float*)(ws + hnbOff);
        float* partials = (float*)(ws + partOff);

        k_prep<<<Z, 256, 0, stream>>>(adj, maskbf, idg, hnb, Z);
        long n8 = (long)B * Z / 8;
        k_conv<<<2048, 256, 0, stream>>>(ctemps, (uint4*)cbf, n8);
        k_gemm<<<nblk, NT, 0, stream>>>(cbf, maskbf, preds, targets, idg, hnb, partials, B, Z, Z);
        k_finalize<<<1, 256, 0, stream>>>(partials, nblk, out, invBZ);
    } else {
        float* acc2 = (float*)d_ws;
        k_zero2<<<1, 64, 0, stream>>>(acc2);
        int nzb = (Z + 255) / 256;
        k_fallback<<<B * nzb, 256, (size_t)Z * 4, stream>>>(preds, targets, ctemps, adj, acc2, B, Z);
        k_finalize<<<1, 256, 0, stream>>>(acc2, 1, out, invBZ);
    }
}